// Round 1
// baseline (740.011 us; speedup 1.0000x reference)
//
#include <hip/hip_runtime.h>
#include <math.h>

#define NPTS   65536
#define DIM    64
#define HID    128
#define NPB    4096   // points per batch
#define KNN    16
#define TS     512    // position tile size
#define CAP    24     // per-thread LDS candidate buffer capacity

// Exact top-16 rebuild from the per-thread LDS candidate buffer.
// Lexicographic (dist, index) worst-tracking so ties evict correctly.
__device__ __forceinline__ void drain_buf(
    const float* __restrict__ bufd, const int* __restrict__ bufi, int tid,
    float (&bd)[KNN], int (&bi)[KNN],
    float& wv, int& wi, int& ws, int& cnt)
{
    for (int t = 0; t < CAP; ++t) {
        if (__ballot(t < cnt) == 0ull) break;
        float d = bufd[t * 256 + tid];
        int   g = bufi[t * 256 + tid];
        bool act = (t < cnt) && ((d < wv) || ((d == wv) && (g < wi)));
        if (act) {
            #pragma unroll
            for (int k = 0; k < KNN; ++k) {
                bd[k] = (k == ws) ? d : bd[k];
                bi[k] = (k == ws) ? g : bi[k];
            }
            wv = bd[0]; wi = bi[0]; ws = 0;
            #pragma unroll
            for (int k = 1; k < KNN; ++k) {
                bool w = (bd[k] > wv) || ((bd[k] == wv) && (bi[k] > wi));
                wv = w ? bd[k] : wv;
                wi = w ? bi[k] : wi;
                ws = w ? k : ws;
            }
        }
    }
    cnt = 0;
}

__global__ __launch_bounds__(256) void gin_fused(
    const float* __restrict__ x, const float* __restrict__ pos,
    const float* __restrict__ W1, const float* __restrict__ b1,
    const float* __restrict__ W2, const float* __restrict__ b2,
    float* __restrict__ out)
{
    #pragma clang fp contract(off)
    // 64 KB LDS, phase-aliased:
    //  phase 1 (KNN): px/py/pz/psq tile (8 KB) + per-thread candidate buffers (48 KB)
    //  phase 2 (MLP): W1^T (32 KB) + W2 (32 KB)
    __shared__ float smem[16384];

    float* px   = smem;
    float* py   = smem + TS;
    float* pz   = smem + 2 * TS;
    float* psq  = smem + 3 * TS;
    float* bufd = smem + 4 * TS;                       // CAP*256 floats
    int*   bufi = (int*)(smem + 4 * TS + CAP * 256);   // CAP*256 ints

    const int tid   = threadIdx.x;
    const int batch = blockIdx.x >> 4;          // 16 blocks per batch
    const int qloc  = ((blockIdx.x & 15) << 8) + tid;
    const int bbase = batch * NPB;
    const int qglob = bbase + qloc;

    // Query point. Same formula/order as numpy ref (contract off => no fma fusion).
    float qx = pos[3 * qglob + 0];
    float qy = pos[3 * qglob + 1];
    float qz = pos[3 * qglob + 2];
    float qs = (qx * qx + qy * qy) + qz * qz;

    float bd[KNN]; int bi[KNN];
    #pragma unroll
    for (int k = 0; k < KNN; ++k) { bd[k] = INFINITY; bi[k] = 0x7FFFFFFF; }
    float wv = INFINITY; int wi = 0x7FFFFFFF; int ws = 0;
    int cnt = 0;

    // ---------------- phase 1: exact 16-NN ----------------
    for (int tb = 0; tb < NPB; tb += TS) {
        __syncthreads();
        for (int t = tid; t < TS; t += 256) {
            int g = (bbase + tb + t) * 3;
            float ax = pos[g], ay = pos[g + 1], az = pos[g + 2];
            px[t] = ax; py[t] = ay; pz[t] = az;
            psq[t] = (ax * ax + ay * ay) + az * az;
        }
        __syncthreads();

        float4 X = *(const float4*)(px);
        float4 Y = *(const float4*)(py);
        float4 Z = *(const float4*)(pz);
        float4 S = *(const float4*)(psq);

        for (int j = 0; j < TS; j += 4) {
            int jn = (j + 4) & (TS - 1);            // wraps to 0 on last iter (unused)
            float4 Xn = *(const float4*)(px + jn);
            float4 Yn = *(const float4*)(py + jn);
            float4 Zn = *(const float4*)(pz + jn);
            float4 Sn = *(const float4*)(psq + jn);

            {   float dot = (X.x * qx + Y.x * qy) + Z.x * qz;
                float d2  = (qs + S.x) - 2.0f * dot;
                int gj = tb + j + 0;
                if ((d2 < wv) & (gj != qloc)) {
                    bufd[cnt * 256 + tid] = d2; bufi[cnt * 256 + tid] = gj; ++cnt; } }
            {   float dot = (X.y * qx + Y.y * qy) + Z.y * qz;
                float d2  = (qs + S.y) - 2.0f * dot;
                int gj = tb + j + 1;
                if ((d2 < wv) & (gj != qloc)) {
                    bufd[cnt * 256 + tid] = d2; bufi[cnt * 256 + tid] = gj; ++cnt; } }
            {   float dot = (X.z * qx + Y.z * qy) + Z.z * qz;
                float d2  = (qs + S.z) - 2.0f * dot;
                int gj = tb + j + 2;
                if ((d2 < wv) & (gj != qloc)) {
                    bufd[cnt * 256 + tid] = d2; bufi[cnt * 256 + tid] = gj; ++cnt; } }
            {   float dot = (X.w * qx + Y.w * qy) + Z.w * qz;
                float d2  = (qs + S.w) - 2.0f * dot;
                int gj = tb + j + 3;
                if ((d2 < wv) & (gj != qloc)) {
                    bufd[cnt * 256 + tid] = d2; bufi[cnt * 256 + tid] = gj; ++cnt; } }

            X = Xn; Y = Yn; Z = Zn; S = Sn;

            // headroom = 4 appends per group; drain before overflow is possible
            if (__ballot(cnt >= CAP - 4) != 0ull)
                drain_buf(bufd, bufi, tid, bd, bi, wv, wi, ws, cnt);
        }
    }
    drain_buf(bufd, bufi, tid, bd, bi, wv, wi, ws, cnt);

    __syncthreads();   // all waves done with phase-1 LDS before re-aliasing

    // ---------------- phase 2: gather + MLP ----------------
    float* w1t = smem;               // [HID][DIM] = W1 transposed
    float* w2s = smem + HID * DIM;   // [HID][DIM] = W2 as-is

    for (int e = tid; e < HID * DIM; e += 256) {
        int dd = e >> 7;             // e = dd*128 + jj  (coalesced read of W1)
        int jj = e & (HID - 1);
        w1t[jj * DIM + dd] = W1[e];
        w2s[e] = W2[e];
    }
    __syncthreads();

    const int r = qglob;
    float inv[DIM];
    {
        const float4* xr = (const float4*)(x + (size_t)r * DIM);
        #pragma unroll
        for (int c = 0; c < DIM / 4; ++c) {
            float4 v = xr[c];
            inv[4*c] = v.x; inv[4*c+1] = v.y; inv[4*c+2] = v.z; inv[4*c+3] = v.w;
        }
        #pragma unroll 2
        for (int k = 0; k < KNN; ++k) {
            const float4* nr = (const float4*)(x + (size_t)(bbase + bi[k]) * DIM);
            #pragma unroll
            for (int c = 0; c < DIM / 4; ++c) {
                float4 v = nr[c];
                inv[4*c]   += v.x; inv[4*c+1] += v.y;
                inv[4*c+2] += v.z; inv[4*c+3] += v.w;
            }
        }
    }

    float acc[DIM];
    #pragma unroll
    for (int c = 0; c < DIM / 4; ++c) {
        float4 v = ((const float4*)b2)[c];
        acc[4*c] = v.x; acc[4*c+1] = v.y; acc[4*c+2] = v.z; acc[4*c+3] = v.w;
    }

    #pragma unroll 2
    for (int j = 0; j < HID; ++j) {
        const float4* wr = (const float4*)(w1t + j * DIM);
        float s0 = 0.f, s1 = 0.f, s2 = 0.f, s3 = 0.f;
        #pragma unroll
        for (int c = 0; c < DIM / 4; ++c) {
            float4 w = wr[c];
            s0 = fmaf(w.x, inv[4*c],   s0);
            s1 = fmaf(w.y, inv[4*c+1], s1);
            s2 = fmaf(w.z, inv[4*c+2], s2);
            s3 = fmaf(w.w, inv[4*c+3], s3);
        }
        float h = (s0 + s1) + (s2 + s3) + b1[j];
        h = fmaxf(h, 0.0f);
        const float4* w2r = (const float4*)(w2s + j * DIM);
        #pragma unroll
        for (int c = 0; c < DIM / 4; ++c) {
            float4 w = w2r[c];
            acc[4*c]   = fmaf(h, w.x, acc[4*c]);
            acc[4*c+1] = fmaf(h, w.y, acc[4*c+1]);
            acc[4*c+2] = fmaf(h, w.z, acc[4*c+2]);
            acc[4*c+3] = fmaf(h, w.w, acc[4*c+3]);
        }
    }

    float4* o = (float4*)(out + (size_t)r * DIM);
    #pragma unroll
    for (int c = 0; c < DIM / 4; ++c)
        o[c] = make_float4(acc[4*c], acc[4*c+1], acc[4*c+2], acc[4*c+3]);
}

extern "C" void kernel_launch(void* const* d_in, const int* in_sizes, int n_in,
                              void* d_out, int out_size, void* d_ws, size_t ws_size,
                              hipStream_t stream) {
    (void)in_sizes; (void)n_in; (void)d_ws; (void)ws_size; (void)out_size;
    const float* x   = (const float*)d_in[0];
    const float* pos = (const float*)d_in[1];
    // d_in[2] = batch indices: deterministic (i // (N/B)), not needed
    const float* W1  = (const float*)d_in[3];
    const float* b1  = (const float*)d_in[4];
    const float* W2  = (const float*)d_in[5];
    const float* b2  = (const float*)d_in[6];
    float* out = (float*)d_out;

    gin_fused<<<dim3(256), dim3(256), 0, stream>>>(x, pos, W1, b1, W2, b2, out);
}

// Round 2
// 698.846 us; speedup vs baseline: 1.0589x; 1.0589x over previous
//
#include <hip/hip_runtime.h>
#include <math.h>

#define NPTS   65536
#define DIM    64
#define HID    128
#define NPB    4096   // points per batch
#define KNN    16
#define SEG    1024   // candidates per wave-segment (NPB/4)
#define TS     256    // position tile size per segment
#define CAP    12     // per-thread LDS candidate buffer capacity

// Lexicographic (dist, index) insert into running top-16.
__device__ __forceinline__ void lex_insert(float d, int g,
    float (&bd)[KNN], int (&bi)[KNN], float& wv, int& wi, int& ws)
{
    bool act = (d < wv) || ((d == wv) && (g < wi));
    if (act) {
        #pragma unroll
        for (int k = 0; k < KNN; ++k) {
            bd[k] = (k == ws) ? d : bd[k];
            bi[k] = (k == ws) ? g : bi[k];
        }
        wv = bd[0]; wi = bi[0]; ws = 0;
        #pragma unroll
        for (int k = 1; k < KNN; ++k) {
            bool w2 = (bd[k] > wv) || ((bd[k] == wv) && (bi[k] > wi));
            wv = w2 ? bd[k] : wv;
            wi = w2 ? bi[k] : wi;
            ws = w2 ? k : ws;
        }
    }
}

__device__ __forceinline__ void drain_buf(
    const float* __restrict__ bufd, const int* __restrict__ bufi, int tid,
    float (&bd)[KNN], int (&bi)[KNN],
    float& wv, int& wi, int& ws, int& cnt)
{
    for (int t = 0; t < CAP; ++t) {
        if (__ballot(t < cnt) == 0ull) break;
        float d = bufd[t * 256 + tid];
        int   g = bufi[t * 256 + tid];
        if (t < cnt) lex_insert(d, g, bd, bi, wv, wi, ws);
    }
    cnt = 0;
}

// Kernel 1: exact 16-NN (segment-split, 4 waves per 64 queries) + gather + agg.
// Writes h = x + sum(neighbors) into agg_out (= d_out, overwritten by MLP kernel).
__global__ __launch_bounds__(256, 4) void knn_agg(
    const float* __restrict__ x, const float* __restrict__ pos,
    float* __restrict__ agg_out)
{
    #pragma clang fp contract(off)
    // 40 KB LDS: tiles (16 KB, per-wave private) + candidate buffers (24 KB).
    // After KNN, aliased as the merge arrays (stride-65 padded, conflict-free).
    __shared__ float smem[10240];

    const int tid = threadIdx.x;
    const int w   = tid >> 6;      // wave = segment
    const int l   = tid & 63;      // lane = query within block's 64

    const int qb     = blockIdx.x;        // 1024 blocks x 64 queries
    const int batch  = qb >> 6;           // 64 blocks per batch
    const int bbase  = batch << 12;       // batch * 4096
    const int qlocal = ((qb & 63) << 6) + l;
    const int qglob  = bbase + qlocal;

    float* tx  = smem + w * 1024;         // per-wave tile region
    float* ty  = tx + 256;
    float* tz  = tx + 512;
    float* tsq = tx + 768;
    float* bufd = smem + 4096;                       // CAP*256 floats
    int*   bufi = (int*)(smem + 4096 + CAP * 256);   // CAP*256 ints

    // Query point; same op order as numpy ref (contract off => no fma fusion).
    float qx = pos[3 * qglob + 0];
    float qy = pos[3 * qglob + 1];
    float qz = pos[3 * qglob + 2];
    float qs = (qx * qx + qy * qy) + qz * qz;

    float bd[KNN]; int bi[KNN];
    #pragma unroll
    for (int k = 0; k < KNN; ++k) { bd[k] = INFINITY; bi[k] = 0x7FFFFFFF; }
    float wv = INFINITY; int wi = 0x7FFFFFFF; int ws = 0;
    int cnt = 0;

    const int segbase = w << 10;          // segment start within batch

    for (int tb = 0; tb < SEG; tb += TS) {
        // Per-wave tile load: no block barrier needed (wave-private region;
        // DS ops from one wave are processed in order).
        #pragma unroll
        for (int m = 0; m < 4; ++m) {
            int t = (m << 6) + l;
            int g = (bbase + segbase + tb + t) * 3;
            float ax = pos[g], ay = pos[g + 1], az = pos[g + 2];
            tx[t] = ax; ty[t] = ay; tz[t] = az;
            tsq[t] = (ax * ax + ay * ay) + az * az;
        }

        for (int j = 0; j < TS; j += 4) {
            float4 X = *(const float4*)(tx + j);
            float4 Y = *(const float4*)(ty + j);
            float4 Z = *(const float4*)(tz + j);
            float4 S = *(const float4*)(tsq + j);
            int cb = segbase + tb + j;

            {   float dot = (X.x * qx + Y.x * qy) + Z.x * qz;
                float d2  = (qs + S.x) - 2.0f * dot;
                int cj = cb + 0;
                if ((d2 < wv) & (cj != qlocal)) {
                    bufd[cnt * 256 + tid] = d2; bufi[cnt * 256 + tid] = cj; ++cnt; } }
            {   float dot = (X.y * qx + Y.y * qy) + Z.y * qz;
                float d2  = (qs + S.y) - 2.0f * dot;
                int cj = cb + 1;
                if ((d2 < wv) & (cj != qlocal)) {
                    bufd[cnt * 256 + tid] = d2; bufi[cnt * 256 + tid] = cj; ++cnt; } }
            {   float dot = (X.z * qx + Y.z * qy) + Z.z * qz;
                float d2  = (qs + S.z) - 2.0f * dot;
                int cj = cb + 2;
                if ((d2 < wv) & (cj != qlocal)) {
                    bufd[cnt * 256 + tid] = d2; bufi[cnt * 256 + tid] = cj; ++cnt; } }
            {   float dot = (X.w * qx + Y.w * qy) + Z.w * qz;
                float d2  = (qs + S.w) - 2.0f * dot;
                int cj = cb + 3;
                if ((d2 < wv) & (cj != qlocal)) {
                    bufd[cnt * 256 + tid] = d2; bufi[cnt * 256 + tid] = cj; ++cnt; } }

            // headroom = 4 appends per group; CAP=12 so drain at cnt>=8
            if (__ballot(cnt >= CAP - 4) != 0ull)
                drain_buf(bufd, bufi, tid, bd, bi, wv, wi, ws, cnt);
        }
    }
    drain_buf(bufd, bufi, tid, bd, bi, wv, wi, ws, cnt);

    __syncthreads();   // buffers/tiles dead; re-alias as merge arrays

    // Merge arrays: 64 queries x 64 entries, row stride 65 (conflict-free).
    float* md = smem;                    // 4160 floats
    int*   mi = (int*)(smem + 4160);     // 4160 ints

    #pragma unroll
    for (int k = 0; k < KNN; ++k) {
        md[l * 65 + (w << 4) + k] = bd[k];
        mi[l * 65 + (w << 4) + k] = bi[k];
    }
    __syncthreads();

    // Merge the 4 segment top-16s -> exact top-16. One thread per query.
    if (tid < 64) {
        #pragma unroll
        for (int k = 0; k < KNN; ++k) { bd[k] = INFINITY; bi[k] = 0x7FFFFFFF; }
        wv = INFINITY; wi = 0x7FFFFFFF; ws = 0;
        for (int c = 0; c < 64; ++c) {
            float d = md[tid * 65 + c];
            int   g = mi[tid * 65 + c];
            lex_insert(d, g, bd, bi, wv, wi, ws);
        }
        #pragma unroll
        for (int k = 0; k < KNN; ++k) mi[tid * 65 + k] = bi[k];
    }
    __syncthreads();

    // Gather + aggregate: 4 threads per row, 16 cols each. h = x + sum(nb).
    {
        const int r = tid >> 2;          // row within block
        const int p = tid & 3;           // col slice
        const int q = (qb << 6) + r;     // global row
        const int cb = p << 4;

        int idxs[KNN];
        #pragma unroll
        for (int k = 0; k < KNN; ++k) idxs[k] = mi[r * 65 + k];

        float4 a0 = *(const float4*)(x + q * DIM + cb + 0);
        float4 a1 = *(const float4*)(x + q * DIM + cb + 4);
        float4 a2 = *(const float4*)(x + q * DIM + cb + 8);
        float4 a3 = *(const float4*)(x + q * DIM + cb + 12);

        #pragma unroll 4
        for (int k = 0; k < KNN; ++k) {
            const float* nr = x + (bbase + idxs[k]) * DIM + cb;
            float4 v0 = *(const float4*)(nr + 0);
            float4 v1 = *(const float4*)(nr + 4);
            float4 v2 = *(const float4*)(nr + 8);
            float4 v3 = *(const float4*)(nr + 12);
            a0.x += v0.x; a0.y += v0.y; a0.z += v0.z; a0.w += v0.w;
            a1.x += v1.x; a1.y += v1.y; a1.z += v1.z; a1.w += v1.w;
            a2.x += v2.x; a2.y += v2.y; a2.z += v2.z; a2.w += v2.w;
            a3.x += v3.x; a3.y += v3.y; a3.z += v3.z; a3.w += v3.w;
        }

        float* o = agg_out + q * DIM + cb;
        *(float4*)(o + 0)  = a0;
        *(float4*)(o + 4)  = a1;
        *(float4*)(o + 8)  = a2;
        *(float4*)(o + 12) = a3;
    }
}

// Kernel 2: MLP out = relu(h @ W1 + b1) @ W2 + b2, in-place on d_out.
// 2 threads per row (half the hidden units each), shfl_xor combine.
__global__ __launch_bounds__(256, 2) void mlp(
    const float* __restrict__ W1, const float* __restrict__ b1,
    const float* __restrict__ W2, const float* __restrict__ b2,
    float* __restrict__ io)
{
    __shared__ float smem[16384];        // w1t [128][64] + w2 [128][64] = 64 KB
    float* w1t = smem;
    float* w2s = smem + HID * DIM;

    const int tid = threadIdx.x;
    // Conflict-free LDS writes; strided (cached) global reads for the transpose.
    for (int e = tid; e < HID * DIM; e += 256) {
        w1t[e] = W1[(e & 63) * HID + (e >> 6)];   // w1t[j*64+d] = W1[d][j]
        w2s[e] = W2[e];
    }
    __syncthreads();

    const int row  = blockIdx.x * 128 + (tid >> 1);
    const int half = tid & 1;

    float inv[DIM];
    {
        const float4* xr = (const float4*)(io + row * DIM);
        #pragma unroll
        for (int c = 0; c < DIM / 4; ++c) {
            float4 v = xr[c];
            inv[4*c] = v.x; inv[4*c+1] = v.y; inv[4*c+2] = v.z; inv[4*c+3] = v.w;
        }
    }

    float acc[DIM];
    #pragma unroll
    for (int c = 0; c < DIM; ++c) acc[c] = 0.0f;

    const int jbase = half * (HID / 2);
    #pragma unroll 2
    for (int jj = 0; jj < HID / 2; ++jj) {
        const int j = jbase + jj;
        const float4* wr = (const float4*)(w1t + j * DIM);
        float s0 = 0.f, s1 = 0.f, s2 = 0.f, s3 = 0.f;
        #pragma unroll
        for (int c = 0; c < DIM / 4; ++c) {
            float4 ww = wr[c];
            s0 = fmaf(ww.x, inv[4*c],   s0);
            s1 = fmaf(ww.y, inv[4*c+1], s1);
            s2 = fmaf(ww.z, inv[4*c+2], s2);
            s3 = fmaf(ww.w, inv[4*c+3], s3);
        }
        float h = (s0 + s1) + (s2 + s3) + b1[j];
        h = fmaxf(h, 0.0f);
        const float4* w2r = (const float4*)(w2s + j * DIM);
        #pragma unroll
        for (int c = 0; c < DIM / 4; ++c) {
            float4 ww = w2r[c];
            acc[4*c]   = fmaf(h, ww.x, acc[4*c]);
            acc[4*c+1] = fmaf(h, ww.y, acc[4*c+1]);
            acc[4*c+2] = fmaf(h, ww.z, acc[4*c+2]);
            acc[4*c+3] = fmaf(h, ww.w, acc[4*c+3]);
        }
    }

    // Combine the two halves' partial outputs (pairs are adjacent lanes).
    #pragma unroll
    for (int c = 0; c < DIM; ++c) acc[c] += __shfl_xor(acc[c], 1);

    // Each thread stores its half of the output row, plus b2.
    const int cb = half * (DIM / 2);
    float* o = io + row * DIM + cb;
    #pragma unroll
    for (int c = 0; c < DIM / 8; ++c) {          // 8 float4s = 32 floats
        float4 bv = *(const float4*)(b2 + cb + 4 * c);
        float4 r;
        r.x = acc[cb + 4*c + 0] + bv.x;
        r.y = acc[cb + 4*c + 1] + bv.y;
        r.z = acc[cb + 4*c + 2] + bv.z;
        r.w = acc[cb + 4*c + 3] + bv.w;
        *(float4*)(o + 4 * c) = r;
    }
}

extern "C" void kernel_launch(void* const* d_in, const int* in_sizes, int n_in,
                              void* d_out, int out_size, void* d_ws, size_t ws_size,
                              hipStream_t stream) {
    (void)in_sizes; (void)n_in; (void)d_ws; (void)ws_size; (void)out_size;
    const float* x   = (const float*)d_in[0];
    const float* pos = (const float*)d_in[1];
    // d_in[2] = batch indices: deterministic (i // (N/B)), not needed
    const float* W1  = (const float*)d_in[3];
    const float* b1  = (const float*)d_in[4];
    const float* W2  = (const float*)d_in[5];
    const float* b2  = (const float*)d_in[6];
    float* out = (float*)d_out;

    knn_agg<<<dim3(1024), dim3(256), 0, stream>>>(x, pos, out);
    mlp<<<dim3(512), dim3(256), 0, stream>>>(W1, b1, W2, b2, out);
}

// Round 4
// 407.748 us; speedup vs baseline: 1.8149x; 1.7139x over previous
//
#include <hip/hip_runtime.h>
#include <math.h>

#define DIM  64
#define HID  128
#define NPB  4096   // points per batch
#define KNN  16
#define SEG  1024   // candidates per wave-segment (NPB/4)
#define TSZ  128    // position tile size per segment
#define CAP  12     // per-thread LDS candidate buffer capacity

typedef unsigned long long u64;

// ---- monotonic (dist,idx) -> u64 key; smaller key = lex-better neighbor ----
__device__ __forceinline__ u64 pack_key(float d, unsigned idx) {
    unsigned u = __float_as_uint(d);
    unsigned m = u ^ ((unsigned)(((int)u) >> 31) | 0x80000000u);
    return ((u64)m << 32) | idx;
}
__device__ __forceinline__ float key_dist(u64 k) {
    unsigned m = (unsigned)(k >> 32);
    unsigned u = (m & 0x80000000u) ? (m ^ 0x80000000u) : ~m;
    return __uint_as_float(u);
}

// Insert key into ascending-sorted b[16], dropping the old max.
__device__ __forceinline__ void sorted_insert(u64 (&b)[KNN], u64 key) {
    u64 c = key;
    #pragma unroll
    for (int i = 0; i < KNN; ++i) {
        bool lt = c < b[i];
        u64 lo = lt ? c : b[i];
        u64 hi = lt ? b[i] : c;
        b[i] = lo; c = hi;
    }
}

__device__ __forceinline__ void drain_buf(const u64* bufe, int tid,
                                          u64 (&b)[KNN], int& cnt, float& wv) {
    for (int t = 0; t < CAP; ++t) {
        if (__ballot(t < cnt) == 0ull) break;
        u64 e = bufe[t * 256 + tid];
        unsigned dbits = (unsigned)e;
        unsigned idx   = (unsigned)(e >> 32);
        unsigned m = dbits ^ ((unsigned)(((int)dbits) >> 31) | 0x80000000u);
        u64 key = ((u64)m << 32) | idx;
        if ((t < cnt) && (key < b[KNN - 1])) sorted_insert(b, key);
    }
    cnt = 0;
    wv = key_dist(b[KNN - 1]);
}

// float2 helpers with contraction OFF inside (bit-match numpy's mul/add seq;
// pairs give the compiler v_pk_mul_f32 / v_pk_add_f32).
struct f2 { float a, b; };
__device__ __forceinline__ f2 f2mul(f2 x, float s) {
    #pragma clang fp contract(off)
    f2 r; r.a = x.a * s; r.b = x.b * s; return r;
}
__device__ __forceinline__ f2 f2add(f2 x, f2 y) {
    #pragma clang fp contract(off)
    f2 r; r.a = x.a + y.a; r.b = x.b + y.b; return r;
}
__device__ __forceinline__ f2 f2adds(f2 x, float s) {
    #pragma clang fp contract(off)
    f2 r; r.a = s + x.a; r.b = s + x.b; return r;
}
__device__ __forceinline__ f2 f2sub(f2 x, f2 y) {
    #pragma clang fp contract(off)
    f2 r; r.a = x.a - y.a; r.b = x.b - y.b; return r;
}

// Whole per-wave segment scan. CHECK=true only for the one wave whose segment
// contains the block's 64 query self-indices.
template<bool CHECK>
__device__ __forceinline__ void knn_scan(
    const float* __restrict__ pos, int bbase, int segbase, int qlocal, int l,
    float qx, float qy, float qz, float qs,
    float* tx, float* ty, float* tz, float* ts,
    u64* bufe, int tid, u64 (&b)[KNN])
{
    #pragma clang fp contract(off)
    int cnt = 0;
    float wv;

    // ---- tile 0 load (wave-private region; in-wave DS ordering suffices) ----
    {
        #pragma unroll
        for (int m = 0; m < 2; ++m) {
            int t = (m << 6) + l;
            int g = (bbase + segbase + t) * 3;
            float ax = pos[g], ay = pos[g + 1], az = pos[g + 2];
            tx[t] = ax; ty[t] = ay; tz[t] = az;
            ts[t] = (ax * ax + ay * ay) + az * az;
        }
    }

    // ---- seed: first 16 candidates straight into the sorted set ----
    #pragma unroll
    for (int k = 0; k < KNN; ++k) b[k] = 0xFFFFFFFFFFFFFFFFull;
    for (int jj = 0; jj < KNN; ++jj) {
        float ax = tx[jj], ay = ty[jj], az = tz[jj], as = ts[jj];
        float dot = (ax * qx + ay * qy) + az * qz;
        float d2  = (qs + as) - 2.0f * dot;
        int cj = segbase + jj;
        if (cj == qlocal) d2 = INFINITY;          // self -> never selected
        sorted_insert(b, pack_key(d2, (unsigned)cj));
    }
    wv = key_dist(b[KNN - 1]);

    // ---- main scan ----
    int jstart = KNN;
    for (int tb = 0; tb < SEG; tb += TSZ) {
        if (tb > 0) {
            #pragma unroll
            for (int m = 0; m < 2; ++m) {
                int t = (m << 6) + l;
                int g = (bbase + segbase + tb + t) * 3;
                float ax = pos[g], ay = pos[g + 1], az = pos[g + 2];
                tx[t] = ax; ty[t] = ay; tz[t] = az;
                ts[t] = (ax * ax + ay * ay) + az * az;
            }
        }
        for (int j = jstart; j < TSZ; j += 4) {
            float4 X = *(const float4*)(tx + j);
            float4 Y = *(const float4*)(ty + j);
            float4 Z = *(const float4*)(tz + j);
            float4 S = *(const float4*)(ts + j);
            const int c0 = segbase + tb + j;

            // pair 0: candidates c0, c0+1
            {
                f2 Px = {X.x, X.y}, Py = {Y.x, Y.y}, Pz = {Z.x, Z.y}, Ps = {S.x, S.y};
                f2 dot = f2add(f2add(f2mul(Px, qx), f2mul(Py, qy)), f2mul(Pz, qz));
                f2 s1 = f2adds(Ps, qs);
                f2 d2 = f2sub(s1, f2mul(dot, 2.0f));
                if (CHECK) {
                    if (c0     == qlocal) d2.a = INFINITY;
                    if (c0 + 1 == qlocal) d2.b = INFINITY;
                }
                if (d2.a <= wv) {
                    bufe[cnt * 256 + tid] =
                        ((u64)(unsigned)(c0) << 32) | __float_as_uint(d2.a);
                    ++cnt;
                }
                if (d2.b <= wv) {
                    bufe[cnt * 256 + tid] =
                        ((u64)(unsigned)(c0 + 1) << 32) | __float_as_uint(d2.b);
                    ++cnt;
                }
            }
            // pair 1: candidates c0+2, c0+3
            {
                f2 Px = {X.z, X.w}, Py = {Y.z, Y.w}, Pz = {Z.z, Z.w}, Ps = {S.z, S.w};
                f2 dot = f2add(f2add(f2mul(Px, qx), f2mul(Py, qy)), f2mul(Pz, qz));
                f2 s1 = f2adds(Ps, qs);
                f2 d2 = f2sub(s1, f2mul(dot, 2.0f));
                if (CHECK) {
                    if (c0 + 2 == qlocal) d2.a = INFINITY;
                    if (c0 + 3 == qlocal) d2.b = INFINITY;
                }
                if (d2.a <= wv) {
                    bufe[cnt * 256 + tid] =
                        ((u64)(unsigned)(c0 + 2) << 32) | __float_as_uint(d2.a);
                    ++cnt;
                }
                if (d2.b <= wv) {
                    bufe[cnt * 256 + tid] =
                        ((u64)(unsigned)(c0 + 3) << 32) | __float_as_uint(d2.b);
                    ++cnt;
                }
            }

            if (__ballot(cnt >= CAP - 4) != 0ull)
                drain_buf(bufe, tid, b, cnt, wv);
        }
        jstart = 0;
    }
    drain_buf(bufe, tid, b, cnt, wv);
}

// Kernel 1: exact 16-NN + gather + aggregate. Writes h = x + sum(nb) to agg_out.
__global__ __launch_bounds__(256, 4) void knn_agg(
    const float* __restrict__ x, const float* __restrict__ pos,
    float* __restrict__ agg_out)
{
    // 32 KB LDS: phase1 = tiles (8 KB) + u64 candidate buffers (24 KB);
    // phase2 alias = 64x64 u64 merge keys (XOR-swizzled); phase3 alias = idx array.
    __shared__ u64 smem[4096];

    const int tid = threadIdx.x;
    const int w   = tid >> 6;
    const int l   = tid & 63;

    const int qb     = blockIdx.x;          // 1024 blocks x 64 queries
    const int batch  = qb >> 6;
    const int bbase  = batch << 12;
    const int qlocal = ((qb & 63) << 6) + l;
    const int qglob  = bbase + qlocal;

    float* tilef = (float*)smem;
    float* tx = tilef + w * 512;
    float* ty = tx + TSZ;
    float* tz = tx + 2 * TSZ;
    float* ts = tx + 3 * TSZ;
    u64* bufe = smem + 1024;                // 3072 u64 = 24 KB

    float qx, qy, qz, qs;
    {
        #pragma clang fp contract(off)
        qx = pos[3 * qglob + 0];
        qy = pos[3 * qglob + 1];
        qz = pos[3 * qglob + 2];
        qs = (qx * qx + qy * qy) + qz * qz;
    }

    u64 b[KNN];
    const int segbase = w << 10;
    const int wself   = (qb & 63) >> 4;     // wave whose segment holds the selves
    if (w == wself)
        knn_scan<true >(pos, bbase, segbase, qlocal, l, qx, qy, qz, qs,
                        tx, ty, tz, ts, bufe, tid, b);
    else
        knn_scan<false>(pos, bbase, segbase, qlocal, l, qx, qy, qz, qs,
                        tx, ty, tz, ts, bufe, tid, b);

    __syncthreads();                         // phase-1 LDS dead; re-alias

    // ---- merge: 64 queries x 64 keys, XOR-swizzled (conflict-light) ----
    u64* kb = smem;
    #pragma unroll
    for (int k = 0; k < KNN; ++k) {
        int slot = (w << 4) + k;
        kb[(l << 6) + (slot ^ (l & 31))] = b[k];
    }
    __syncthreads();

    if (tid < 64) {
        u64 m2[KNN];
        #pragma unroll
        for (int c = 0; c < KNN; ++c)
            m2[c] = kb[(tid << 6) + (c ^ (tid & 31))];   // wave-0 list, sorted
        for (int c = KNN; c < 64; ++c) {
            u64 kk = kb[(tid << 6) + (c ^ (tid & 31))];
            if (kk < m2[KNN - 1]) sorted_insert(m2, kk);
        }
        int* mi = (int*)smem;                // same-wave ordering: reads done above
        #pragma unroll
        for (int k = 0; k < KNN; ++k)
            mi[tid * 17 + k] = (int)(m2[k] & 0xFFFFFFFFull);
    }
    __syncthreads();

    // ---- gather + aggregate: 4 threads/row, 16 cols each ----
    {
        const int* mi = (const int*)smem;
        const int r  = tid >> 2;
        const int p  = tid & 3;
        const int q  = (qb << 6) + r;
        const int cb = p << 4;

        int idxs[KNN];
        #pragma unroll
        for (int k = 0; k < KNN; ++k) idxs[k] = mi[r * 17 + k];

        float4 a0 = *(const float4*)(x + (size_t)q * DIM + cb + 0);
        float4 a1 = *(const float4*)(x + (size_t)q * DIM + cb + 4);
        float4 a2 = *(const float4*)(x + (size_t)q * DIM + cb + 8);
        float4 a3 = *(const float4*)(x + (size_t)q * DIM + cb + 12);

        #pragma unroll 4
        for (int k = 0; k < KNN; ++k) {
            const float* nr = x + (size_t)(bbase + idxs[k]) * DIM + cb;
            float4 v0 = *(const float4*)(nr + 0);
            float4 v1 = *(const float4*)(nr + 4);
            float4 v2 = *(const float4*)(nr + 8);
            float4 v3 = *(const float4*)(nr + 12);
            a0.x += v0.x; a0.y += v0.y; a0.z += v0.z; a0.w += v0.w;
            a1.x += v1.x; a1.y += v1.y; a1.z += v1.z; a1.w += v1.w;
            a2.x += v2.x; a2.y += v2.y; a2.z += v2.z; a2.w += v2.w;
            a3.x += v3.x; a3.y += v3.y; a3.z += v3.z; a3.w += v3.w;
        }

        float* o = agg_out + (size_t)q * DIM + cb;
        *(float4*)(o + 0)  = a0;
        *(float4*)(o + 4)  = a1;
        *(float4*)(o + 8)  = a2;
        *(float4*)(o + 12) = a3;
    }
}

// Kernel 2: out = relu(h @ W1 + b1) @ W2 + b2, in-place on io (= d_out).
// 32 rows/block, 8 threads/row. Phase A: 16 h-cols/thread -> h in LDS.
// Phase B: 8 out-cols/thread. W1/W2 share one 32 KB LDS region (aliased).
__global__ __launch_bounds__(256, 3) void mlp(
    const float* __restrict__ W1, const float* __restrict__ b1,
    const float* __restrict__ W2, const float* __restrict__ b2,
    float* __restrict__ io)
{
    __shared__ float sm[8192 + 32 * 132];   // W region (32 KB) + h[32][132]
    float* wl = sm;
    float* hl = sm + 8192;

    const int tid = threadIdx.x;
    const int r   = tid >> 3;               // row within block (0..31)
    const int p   = tid & 7;                // slice (0..7)
    const int row = blockIdx.x * 32 + r;

    for (int e = tid; e < HID * DIM; e += 256) wl[e] = W1[e];  // [k][128]
    __syncthreads();

    // x row in registers (8x redundant reads per row; L1/L2-resident)
    float4 x4[16];
    {
        const float4* xr = (const float4*)(io + (size_t)row * DIM);
        #pragma unroll
        for (int i = 0; i < 16; ++i) x4[i] = xr[i];
    }

    // phase A: h[j] for j in [16p, 16p+16)
    {
        float acc[16];
        #pragma unroll
        for (int c = 0; c < 16; ++c) acc[c] = 0.0f;
        const int jb = p << 4;

        #pragma unroll
        for (int kk = 0; kk < 16; ++kk) {
            float4 xv = x4[kk];
            #pragma unroll
            for (int s = 0; s < 4; ++s) {
                const int k = 4 * kk + s;
                const float xs2 = (s == 0) ? xv.x : (s == 1) ? xv.y : (s == 2) ? xv.z : xv.w;
                const float4* wr = (const float4*)(wl + k * HID + jb);
                float4 w0 = wr[0], w1 = wr[1], w2 = wr[2], w3 = wr[3];
                acc[0]  = fmaf(xs2, w0.x, acc[0]);  acc[1]  = fmaf(xs2, w0.y, acc[1]);
                acc[2]  = fmaf(xs2, w0.z, acc[2]);  acc[3]  = fmaf(xs2, w0.w, acc[3]);
                acc[4]  = fmaf(xs2, w1.x, acc[4]);  acc[5]  = fmaf(xs2, w1.y, acc[5]);
                acc[6]  = fmaf(xs2, w1.z, acc[6]);  acc[7]  = fmaf(xs2, w1.w, acc[7]);
                acc[8]  = fmaf(xs2, w2.x, acc[8]);  acc[9]  = fmaf(xs2, w2.y, acc[9]);
                acc[10] = fmaf(xs2, w2.z, acc[10]); acc[11] = fmaf(xs2, w2.w, acc[11]);
                acc[12] = fmaf(xs2, w3.x, acc[12]); acc[13] = fmaf(xs2, w3.y, acc[13]);
                acc[14] = fmaf(xs2, w3.z, acc[14]); acc[15] = fmaf(xs2, w3.w, acc[15]);
            }
        }
        #pragma unroll
        for (int c = 0; c < 16; ++c) {
            float h = acc[c] + b1[jb + c];
            hl[r * 132 + jb + c] = fmaxf(h, 0.0f);
        }
    }
    __syncthreads();

    for (int e = tid; e < HID * DIM; e += 256) wl[e] = W2[e];  // [j][64]
    __syncthreads();

    // phase B: out[c] for c in [8p, 8p+8)
    {
        float acc[8];
        #pragma unroll
        for (int c = 0; c < 8; ++c) acc[c] = 0.0f;
        const int cbb = p << 3;

        #pragma unroll 4
        for (int jj = 0; jj < 32; ++jj) {
            float4 hv = *(const float4*)(hl + r * 132 + 4 * jj);
            #pragma unroll
            for (int s = 0; s < 4; ++s) {
                const int j = 4 * jj + s;
                const float h = (s == 0) ? hv.x : (s == 1) ? hv.y : (s == 2) ? hv.z : hv.w;
                const float4* wr = (const float4*)(wl + j * DIM + cbb);
                float4 w0 = wr[0], w1 = wr[1];
                acc[0] = fmaf(h, w0.x, acc[0]); acc[1] = fmaf(h, w0.y, acc[1]);
                acc[2] = fmaf(h, w0.z, acc[2]); acc[3] = fmaf(h, w0.w, acc[3]);
                acc[4] = fmaf(h, w1.x, acc[4]); acc[5] = fmaf(h, w1.y, acc[5]);
                acc[6] = fmaf(h, w1.z, acc[6]); acc[7] = fmaf(h, w1.w, acc[7]);
            }
        }

        float4 bv0 = *(const float4*)(b2 + cbb);
        float4 bv1 = *(const float4*)(b2 + cbb + 4);
        float4 r0 = make_float4(acc[0] + bv0.x, acc[1] + bv0.y,
                                acc[2] + bv0.z, acc[3] + bv0.w);
        float4 r1 = make_float4(acc[4] + bv1.x, acc[5] + bv1.y,
                                acc[6] + bv1.z, acc[7] + bv1.w);
        float* o = io + (size_t)row * DIM + cbb;
        *(float4*)(o + 0) = r0;
        *(float4*)(o + 4) = r1;
    }
}

extern "C" void kernel_launch(void* const* d_in, const int* in_sizes, int n_in,
                              void* d_out, int out_size, void* d_ws, size_t ws_size,
                              hipStream_t stream) {
    (void)in_sizes; (void)n_in; (void)d_ws; (void)ws_size; (void)out_size;
    const float* x   = (const float*)d_in[0];
    const float* pos = (const float*)d_in[1];
    // d_in[2] = batch indices: deterministic (i // (N/B)), not needed
    const float* W1  = (const float*)d_in[3];
    const float* b1  = (const float*)d_in[4];
    const float* W2  = (const float*)d_in[5];
    const float* b2  = (const float*)d_in[6];
    float* out = (float*)d_out;

    knn_agg<<<dim3(1024), dim3(256), 0, stream>>>(x, pos, out);
    mlp<<<dim3(2048), dim3(256), 0, stream>>>(W1, b1, W2, b2, out);
}